// Round 6
// baseline (243.578 us; speedup 1.0000x reference)
//
#include <hip/hip_runtime.h>

typedef _Float16 half8 __attribute__((ext_vector_type(8)));
typedef short short8v __attribute__((ext_vector_type(8)));
typedef unsigned short ushort4v __attribute__((ext_vector_type(4)));
typedef float floatx4 __attribute__((ext_vector_type(4)));

#define GLOBAL_AS __attribute__((address_space(1)))
#define LDS_AS __attribute__((address_space(3)))
#define L2E 1.44269504f
#define L2E2 2.88539008f

__device__ __forceinline__ unsigned short f2bf(float f) {
  unsigned int u = __float_as_uint(f);
  unsigned int r = (u + 0x7FFFu + ((u >> 16) & 1u)) >> 16;
  return (unsigned short)r;
}

// ---------------- K1: XBT[j][m] bf16 (m pad 4032, zero); Wt2[j][k] f16 PRE-SCALED by
// log2e (i,f,o gates) / 2*log2e (g gate) for exp2-domain LSTM nonlinearities.
__global__ __launch_bounds__(256) void prep_kernel(
    const float* __restrict__ x, const float* __restrict__ W_ih,
    const float* __restrict__ W_hh, unsigned short* __restrict__ XBT,
    unsigned short* __restrict__ Wt2) {
  int idx = blockIdx.x * 256 + threadIdx.x;
  if (idx < 96 * 1008) {
    int bt = idx / 1008;
    int mg = idx - bt * 1008;
    int m0 = mg * 4;
    int j0 = bt * 2;
    ushort4v c0, c1;
    if (m0 < 4000) {
      const float* px = x + ((size_t)bt * 4000 + m0) * 2;
      float4 v0 = *reinterpret_cast<const float4*>(px);
      float4 v1 = *reinterpret_cast<const float4*>(px + 4);
      c0[0] = f2bf(v0.x); c0[1] = f2bf(v0.z); c0[2] = f2bf(v1.x); c0[3] = f2bf(v1.z);
      c1[0] = f2bf(v0.y); c1[1] = f2bf(v0.w); c1[2] = f2bf(v1.y); c1[3] = f2bf(v1.w);
    } else {
      c0 = ushort4v{0, 0, 0, 0};
      c1 = ushort4v{0, 0, 0, 0};
    }
    *reinterpret_cast<ushort4v*>(&XBT[(size_t)j0 * 4032 + m0]) = c0;
    *reinterpret_cast<ushort4v*>(&XBT[(size_t)(j0 + 1) * 4032 + m0]) = c1;
  } else {
    int widx = idx - 96 * 1008;   // exactly 256*16
    int j = widx >> 4, kq = widx & 15;
    float scale = (j >= 128 && j < 192) ? L2E2 : L2E;
    const float* src = (kq < 8) ? (W_ih + j * 64 + kq * 8)
                                : (W_hh + j * 64 + (kq - 8) * 8);
    float4 v0 = *reinterpret_cast<const float4*>(src);
    float4 v1 = *reinterpret_cast<const float4*>(src + 4);
    half8 h;
    h[0] = (_Float16)(v0.x * scale); h[1] = (_Float16)(v0.y * scale);
    h[2] = (_Float16)(v0.z * scale); h[3] = (_Float16)(v0.w * scale);
    h[4] = (_Float16)(v1.x * scale); h[5] = (_Float16)(v1.y * scale);
    h[6] = (_Float16)(v1.z * scale); h[7] = (_Float16)(v1.w * scale);
    *reinterpret_cast<half8*>(&Wt2[j * 128 + kq * 8]) = h;
  }
}

// ---------------- K2: XGP[ch][n][j] partial = sum_{m in chunk} adj[n][m]*x[m][j]
// M-tile 64, K-tile 32, 7 chunks (6x18 + 1x17 tiles) x 63 n-blocks = 441 blocks.
// Ring-3 LDS, 2-deep prefetch, all staging via global_load_lds (proven mechanism),
// counted vmcnt (5 load-insts/wave/tile).
__global__ __launch_bounds__(256, 2) void gcn_gemm_kernel(
    const float* __restrict__ adj, const unsigned short* __restrict__ XBT,
    float* __restrict__ XGP) {
  __shared__ float Ab[3][2048];            // [64 n][32 k] f32, granule-XOR by (row&7)
  __shared__ unsigned short Bb[3][6144];   // [192 j][32 k] bf16, granule-XOR by ((j>>1)&3)
  int tid = threadIdx.x;
  int w = tid >> 6, lane = tid & 63, l15 = lane & 15, kg = lane >> 4;
  int wr = w >> 1, wc = w & 1;             // 2x2 waves: rows wr*32+, j wc*96+
  int bid = blockIdx.x;
  int ch = bid / 63;                       // 0..6
  int nb = bid - ch * 63;
  int n0 = (nb == 62) ? 3936 : nb * 64;    // last block overlaps (idempotent rewrite)
  int k0 = ch * 576;                       // chunk k origin (18 tiles of 32)
  int nt = (ch == 6) ? 17 : 18;            // 6*18 + 17 = 125 tiles = 4000 k exact

  // A staging: thread stages granules gi = l*256+tid; slot (row,kq) holds logical
  // granule kq ^ (row&7) -> source pre-permuted, LDS dest linear (G21).
  const float* aS[2];
#pragma unroll
  for (int l = 0; l < 2; l++) {
    int gi = l * 256 + tid;
    int row = gi >> 3, kq = gi & 7;
    aS[l] = adj + (size_t)(n0 + row) * 4000 + k0 + ((kq ^ (row & 7)) << 2);
  }
  // B staging: granules gi = q*256+tid; slot (j,gp) holds logical gp ^ ((j>>1)&3)
  const unsigned short* bS[3];
#pragma unroll
  for (int q = 0; q < 3; q++) {
    int gi = q * 256 + tid;
    int j = gi >> 2, gp = gi & 3;
    bS[q] = XBT + (size_t)j * 4032 + k0 + ((gp ^ ((j >> 1) & 3)) << 3);
  }
  // B fragment read offsets (fixed per thread)
  int bOff[6];
#pragma unroll
  for (int ct = 0; ct < 6; ct++) {
    int j = wc * 96 + ct * 16 + l15;
    bOff[ct] = j * 32 + ((kg ^ ((j >> 1) & 3)) << 3);
  }

#define K2_ISSUE(tt, bf)                                                       \
  {                                                                            \
    _Pragma("unroll")                                                          \
    for (int l = 0; l < 2; l++)                                                \
      __builtin_amdgcn_global_load_lds(                                        \
          (const GLOBAL_AS unsigned int*)(aS[l] + (tt) * 32),                  \
          (LDS_AS unsigned int*)&Ab[(bf)][l * 1024 + w * 256], 16, 0, 0);      \
    _Pragma("unroll")                                                          \
    for (int q = 0; q < 3; q++)                                                \
      __builtin_amdgcn_global_load_lds(                                        \
          (const GLOBAL_AS unsigned int*)(bS[q] + (tt) * 32),                  \
          (LDS_AS unsigned int*)&Bb[(bf)][q * 2048 + w * 512], 16, 0, 0);      \
  }

  floatx4 acc[2][6];
#pragma unroll
  for (int rt = 0; rt < 2; rt++)
#pragma unroll
    for (int ct = 0; ct < 6; ct++) acc[rt][ct] = floatx4{0.f, 0.f, 0.f, 0.f};

  K2_ISSUE(0, 0);
  K2_ISSUE(1, 1);
  for (int t = 0; t < nt; t++) {
    int bufc = t % 3;
    if (t + 2 < nt) {
      K2_ISSUE(t + 2, (t + 2) % 3);
      asm volatile("s_waitcnt vmcnt(10)" ::: "memory");   // tile t landed
    } else if (t == nt - 2) {
      asm volatile("s_waitcnt vmcnt(5)" ::: "memory");
    } else {
      asm volatile("s_waitcnt vmcnt(0)" ::: "memory");
    }
    __builtin_amdgcn_sched_barrier(0);
    __builtin_amdgcn_s_barrier();
    asm volatile("" ::: "memory");
#pragma unroll
    for (int rt = 0; rt < 2; rt++) {
      int r = wr * 32 + rt * 16 + l15;
      int rx = (r & 7) << 2;
      float4 u = *reinterpret_cast<const float4*>(&Ab[bufc][r * 32 + ((kg * 8) ^ rx)]);
      float4 v = *reinterpret_cast<const float4*>(&Ab[bufc][r * 32 + ((kg * 8 + 4) ^ rx)]);
      short8v af;
      af[0] = f2bf(u.x); af[1] = f2bf(u.y); af[2] = f2bf(u.z); af[3] = f2bf(u.w);
      af[4] = f2bf(v.x); af[5] = f2bf(v.y); af[6] = f2bf(v.z); af[7] = f2bf(v.w);
#pragma unroll
      for (int ct = 0; ct < 6; ct++) {
        short8v bf = *reinterpret_cast<const short8v*>(&Bb[bufc][bOff[ct]]);
        acc[rt][ct] = __builtin_amdgcn_mfma_f32_16x16x32_bf16(af, bf, acc[rt][ct], 0, 0, 0);
      }
    }
    __builtin_amdgcn_s_barrier();
  }

  // store: XGP[ch][n][j], n-major -> 64B-coalesced quarter-wave stores
  size_t chbase = (size_t)ch * 768000;
#pragma unroll
  for (int rt = 0; rt < 2; rt++)
#pragma unroll
    for (int ct = 0; ct < 6; ct++)
#pragma unroll
      for (int e = 0; e < 4; e++) {
        int n = n0 + wr * 32 + rt * 16 + kg * 4 + e;
        int j = wc * 96 + ct * 16 + l15;
        XGP[chbase + (size_t)n * 192 + j] = acc[rt][ct][e];
      }
}

// ---------------- K3: persistent LSTM, f16 MFMA, exp2-domain gates, bias in acc
__global__ __launch_bounds__(256, 4) void lstm_kernel(
    const float* __restrict__ XGP, const unsigned short* __restrict__ Wt2,
    const float* __restrict__ W_gcn, const float* __restrict__ b_gcn,
    const float* __restrict__ b_ih, const float* __restrict__ b_hh,
    const float* __restrict__ W_out, const float* __restrict__ b_out,
    float* __restrict__ out) {
  __shared__ unsigned short A[32 * 128];  // [row][k] f16, XOR-swizzled; k<64: g, k>=64: h
  __shared__ float xga[24 * 32];
  __shared__ float red[8 * 32];

  int tid = threadIdx.x;
  int w = tid >> 6, lane = tid & 63, l15 = lane & 15, kg = lane >> 4;
  int r0 = blockIdx.x * 32;
  int hidx = w * 16 + l15;

  half8 wf[4][4];
#pragma unroll
  for (int ct = 0; ct < 4; ct++) {
    int j = ct * 64 + hidx;
#pragma unroll
    for (int ks = 0; ks < 4; ks++)
      wf[ct][ks] = *reinterpret_cast<const half8*>(&Wt2[j * 128 + ks * 32 + kg * 8]);
  }
  // pre-scaled biases (match Wt2 scaling)
  float bI = (b_ih[hidx] + b_hh[hidx]) * L2E;
  float bF = (b_ih[64 + hidx] + b_hh[64 + hidx]) * L2E;
  float bG = (b_ih[128 + hidx] + b_hh[128 + hidx]) * L2E2;
  float bO = (b_ih[192 + hidx] + b_hh[192 + hidx]) * L2E;
  float wg0 = W_gcn[2 * hidx], wg1 = W_gcn[2 * hidx + 1], bg = b_gcn[hidx];

  for (int i = tid; i < 32 * 128 / 2; i += 256)
    reinterpret_cast<unsigned int*>(A)[i] = 0u;
  // preload xg: sum 7 K-chunk partials; XGP layout [ch][n][192]
  for (int i = tid; i < 24 * 32; i += 256) {
    int row = i / 24, tc = i - row * 24;
    int g = r0 + row;
    int b = g / 4000, n = g - b * 4000;
    size_t base = (size_t)n * 192 + b * 24 + tc;
    float s = 0.f;
#pragma unroll
    for (int chh = 0; chh < 7; chh++) s += XGP[(size_t)chh * 768000 + base];
    xga[tc * 32 + row] = s;
  }
  float creg[8];
#pragma unroll
  for (int i = 0; i < 8; i++) creg[i] = 0.f;
  __syncthreads();

  for (int t = 0; t < 12; t++) {
    // g-phase
#pragma unroll
    for (int half = 0; half < 2; half++)
#pragma unroll
      for (int rr = 0; rr < 4; rr++) {
        int row = half * 16 + kg * 4 + rr;
        float xg0 = xga[(2 * t) * 32 + row];
        float xg1 = xga[(2 * t + 1) * 32 + row];
        float gv = fmaxf(xg0 * wg0 + xg1 * wg1 + bg, 0.f);
        _Float16 hv = (_Float16)gv;
        A[row * 128 + (hidx ^ ((row & 7) << 3))] = __builtin_bit_cast(unsigned short, hv);
      }
    __syncthreads();

    // gates GEMM [32 x 128] @ [128 x 256], bias preloaded into acc
    floatx4 acc[2][4];
#pragma unroll
    for (int rt = 0; rt < 2; rt++) {
      acc[rt][0] = floatx4{bI, bI, bI, bI};
      acc[rt][1] = floatx4{bF, bF, bF, bF};
      acc[rt][2] = floatx4{bG, bG, bG, bG};
      acc[rt][3] = floatx4{bO, bO, bO, bO};
    }
#pragma unroll
    for (int rt = 0; rt < 2; rt++) {
      int row = rt * 16 + l15;
      int xr = (row & 7) << 3;
      half8 af[4];
#pragma unroll
      for (int ks = 0; ks < 4; ks++)
        af[ks] = *reinterpret_cast<const half8*>(&A[row * 128 + ((ks * 32 + kg * 8) ^ xr)]);
#pragma unroll
      for (int ks = 0; ks < 4; ks++)
#pragma unroll
        for (int ct = 0; ct < 4; ct++)
          acc[rt][ct] = __builtin_amdgcn_mfma_f32_16x16x32_f16(
              af[ks], wf[ct][ks], acc[rt][ct], 0, 0, 0);
    }
    __syncthreads();

    // epilogue: exp2-domain gates (acc already log2e-scaled + biased)
#pragma unroll
    for (int rt = 0; rt < 2; rt++)
#pragma unroll
      for (int e = 0; e < 4; e++) {
        int row = rt * 16 + kg * 4 + e;
        float si = __builtin_amdgcn_rcpf(1.f + __builtin_amdgcn_exp2f(-acc[rt][0][e]));
        float sf = __builtin_amdgcn_rcpf(1.f + __builtin_amdgcn_exp2f(-acc[rt][1][e]));
        float tg = 1.f - 2.f * __builtin_amdgcn_rcpf(1.f + __builtin_amdgcn_exp2f(acc[rt][2][e]));
        float so = __builtin_amdgcn_rcpf(1.f + __builtin_amdgcn_exp2f(-acc[rt][3][e]));
        float c = sf * creg[rt * 4 + e] + si * tg;
        creg[rt * 4 + e] = c;
        float tc = 1.f - 2.f * __builtin_amdgcn_rcpf(1.f + __builtin_amdgcn_exp2f(L2E2 * c));
        float h = so * tc;
        _Float16 hv = (_Float16)h;
        A[row * 128 + ((64 + hidx) ^ ((row & 7) << 3))] = __builtin_bit_cast(unsigned short, hv);
      }
  }
  __syncthreads();

  // output projection
  {
    int rg = tid & 31, kq = tid >> 5;
    float partial = 0.f;
#pragma unroll
    for (int i = 0; i < 8; i++) {
      int k = kq * 8 + i;
      float hv = (float)__builtin_bit_cast(
          _Float16, A[rg * 128 + ((64 + k) ^ ((rg & 7) << 3))]);
      partial += hv * W_out[k];
    }
    red[kq * 32 + rg] = partial;
  }
  __syncthreads();
  if (tid < 32) {
    float s = b_out[0];
#pragma unroll
    for (int i = 0; i < 8; i++) s += red[i * 32 + tid];
    out[r0 + tid] = s;
  }
}

extern "C" void kernel_launch(void* const* d_in, const int* in_sizes, int n_in,
                              void* d_out, int out_size, void* d_ws, size_t ws_size,
                              hipStream_t stream) {
  const float* x     = (const float*)d_in[0];
  const float* adj   = (const float*)d_in[1];
  const float* W_gcn = (const float*)d_in[2];
  const float* b_gcn = (const float*)d_in[3];
  const float* W_ih  = (const float*)d_in[4];
  const float* W_hh  = (const float*)d_in[5];
  const float* b_ih  = (const float*)d_in[6];
  const float* b_hh  = (const float*)d_in[7];
  const float* W_out = (const float*)d_in[8];
  const float* b_out = (const float*)d_in[9];
  float* outp = (float*)d_out;

  float* XGP = (float*)d_ws;                                       // 7*768000 f32 = 21,504,000 B
  unsigned short* XBT = (unsigned short*)((char*)d_ws + 21504000); // 192*4032 bf16
  unsigned short* Wt2 = (unsigned short*)((char*)d_ws + 23052288); // 256*128 f16

  prep_kernel<<<394, 256, 0, stream>>>(x, W_ih, W_hh, XBT, Wt2);
  gcn_gemm_kernel<<<441, 256, 0, stream>>>(adj, XBT, XGP);
  lstm_kernel<<<1000, 256, 0, stream>>>(XGP, Wt2, W_gcn, b_gcn, b_ih, b_hh,
                                        W_out, b_out, outp);
}

// Round 7
// 242.062 us; speedup vs baseline: 1.0063x; 1.0063x over previous
//
#include <hip/hip_runtime.h>

typedef _Float16 half8 __attribute__((ext_vector_type(8)));
typedef short short8v __attribute__((ext_vector_type(8)));
typedef unsigned short ushort4v __attribute__((ext_vector_type(4)));
typedef float floatx4 __attribute__((ext_vector_type(4)));

#define GLOBAL_AS __attribute__((address_space(1)))
#define LDS_AS __attribute__((address_space(3)))
#define L2E 1.44269504f
#define L2E2 2.88539008f

__device__ __forceinline__ unsigned short f2bf(float f) {
  unsigned int u = __float_as_uint(f);
  unsigned int r = (u + 0x7FFFu + ((u >> 16) & 1u)) >> 16;
  return (unsigned short)r;
}

// ---------------- K1: XBT[j][m] bf16 (m pad 4032, zero); Wt2[j][k] f16 PRE-SCALED by
// log2e (i,f,o gates) / 2*log2e (g gate) for exp2-domain LSTM nonlinearities.
__global__ __launch_bounds__(256) void prep_kernel(
    const float* __restrict__ x, const float* __restrict__ W_ih,
    const float* __restrict__ W_hh, unsigned short* __restrict__ XBT,
    unsigned short* __restrict__ Wt2) {
  int idx = blockIdx.x * 256 + threadIdx.x;
  if (idx < 96 * 1008) {
    int bt = idx / 1008;
    int mg = idx - bt * 1008;
    int m0 = mg * 4;
    int j0 = bt * 2;
    ushort4v c0, c1;
    if (m0 < 4000) {
      const float* px = x + ((size_t)bt * 4000 + m0) * 2;
      float4 v0 = *reinterpret_cast<const float4*>(px);
      float4 v1 = *reinterpret_cast<const float4*>(px + 4);
      c0[0] = f2bf(v0.x); c0[1] = f2bf(v0.z); c0[2] = f2bf(v1.x); c0[3] = f2bf(v1.z);
      c1[0] = f2bf(v0.y); c1[1] = f2bf(v0.w); c1[2] = f2bf(v1.y); c1[3] = f2bf(v1.w);
    } else {
      c0 = ushort4v{0, 0, 0, 0};
      c1 = ushort4v{0, 0, 0, 0};
    }
    *reinterpret_cast<ushort4v*>(&XBT[(size_t)j0 * 4032 + m0]) = c0;
    *reinterpret_cast<ushort4v*>(&XBT[(size_t)(j0 + 1) * 4032 + m0]) = c1;
  } else {
    int widx = idx - 96 * 1008;   // exactly 256*16
    int j = widx >> 4, kq = widx & 15;
    float scale = (j >= 128 && j < 192) ? L2E2 : L2E;
    const float* src = (kq < 8) ? (W_ih + j * 64 + kq * 8)
                                : (W_hh + j * 64 + (kq - 8) * 8);
    float4 v0 = *reinterpret_cast<const float4*>(src);
    float4 v1 = *reinterpret_cast<const float4*>(src + 4);
    half8 h;
    h[0] = (_Float16)(v0.x * scale); h[1] = (_Float16)(v0.y * scale);
    h[2] = (_Float16)(v0.z * scale); h[3] = (_Float16)(v0.w * scale);
    h[4] = (_Float16)(v1.x * scale); h[5] = (_Float16)(v1.y * scale);
    h[6] = (_Float16)(v1.z * scale); h[7] = (_Float16)(v1.w * scale);
    *reinterpret_cast<half8*>(&Wt2[j * 128 + kq * 8]) = h;
  }
}

// ---------------- K2: XGP[ch][j][n] partial = sum_{m in chunk} adj[n][m]*x[m][j]
// M-tile 64, K-tile 32, 7 chunks (6x18 + 1x17 tiles) x 63 n-blocks = 441 blocks.
// Ring-3 LDS, 2-deep prefetch, staging via global_load_lds, counted vmcnt.
// MFMA operands SWAPPED (x-frag first) so acc col(l15)=n, row(kg*4+e)=j ->
// stores to [ch][j][n] are 64B-contiguous per 16-lane group (line-exclusive
// per block -> lstm reread has no cross-XCD line sharing).
__global__ __launch_bounds__(256, 2) void gcn_gemm_kernel(
    const float* __restrict__ adj, const unsigned short* __restrict__ XBT,
    float* __restrict__ XGP) {
  __shared__ float Ab[3][2048];            // [64 n][32 k] f32, granule-XOR by (row&7)
  __shared__ unsigned short Bb[3][6144];   // [192 j][32 k] bf16, granule-XOR by ((j>>1)&3)
  int tid = threadIdx.x;
  int w = tid >> 6, lane = tid & 63, l15 = lane & 15, kg = lane >> 4;
  int wr = w >> 1, wc = w & 1;             // 2x2 waves: rows wr*32+, j wc*96+
  int bid = blockIdx.x;
  int ch = bid / 63;                       // 0..6
  int nb = bid - ch * 63;
  int n0 = (nb == 62) ? 3936 : nb * 64;    // last block overlaps (idempotent rewrite)
  int k0 = ch * 576;                       // chunk k origin (18 tiles of 32)
  int nt = (ch == 6) ? 17 : 18;            // 6*18 + 17 = 125 tiles = 4000 k exact

  // A staging: thread stages granules gi = l*256+tid; slot (row,kq) holds logical
  // granule kq ^ (row&7) -> source pre-permuted, LDS dest linear (G21).
  const float* aS[2];
#pragma unroll
  for (int l = 0; l < 2; l++) {
    int gi = l * 256 + tid;
    int row = gi >> 3, kq = gi & 7;
    aS[l] = adj + (size_t)(n0 + row) * 4000 + k0 + ((kq ^ (row & 7)) << 2);
  }
  // B staging: granules gi = q*256+tid; slot (j,gp) holds logical gp ^ ((j>>1)&3)
  const unsigned short* bS[3];
#pragma unroll
  for (int q = 0; q < 3; q++) {
    int gi = q * 256 + tid;
    int j = gi >> 2, gp = gi & 3;
    bS[q] = XBT + (size_t)j * 4032 + k0 + ((gp ^ ((j >> 1) & 3)) << 3);
  }
  // B fragment read offsets (fixed per thread)
  int bOff[6];
#pragma unroll
  for (int ct = 0; ct < 6; ct++) {
    int j = wc * 96 + ct * 16 + l15;
    bOff[ct] = j * 32 + ((kg ^ ((j >> 1) & 3)) << 3);
  }

#define K2_ISSUE(tt, bf)                                                       \
  {                                                                            \
    _Pragma("unroll")                                                          \
    for (int l = 0; l < 2; l++)                                                \
      __builtin_amdgcn_global_load_lds(                                        \
          (const GLOBAL_AS unsigned int*)(aS[l] + (tt) * 32),                  \
          (LDS_AS unsigned int*)&Ab[(bf)][l * 1024 + w * 256], 16, 0, 0);      \
    _Pragma("unroll")                                                          \
    for (int q = 0; q < 3; q++)                                                \
      __builtin_amdgcn_global_load_lds(                                        \
          (const GLOBAL_AS unsigned int*)(bS[q] + (tt) * 32),                  \
          (LDS_AS unsigned int*)&Bb[(bf)][q * 2048 + w * 512], 16, 0, 0);      \
  }

  floatx4 acc[2][6];
#pragma unroll
  for (int rt = 0; rt < 2; rt++)
#pragma unroll
    for (int ct = 0; ct < 6; ct++) acc[rt][ct] = floatx4{0.f, 0.f, 0.f, 0.f};

  K2_ISSUE(0, 0);
  K2_ISSUE(1, 1);
  for (int t = 0; t < nt; t++) {
    int bufc = t % 3;
    if (t + 2 < nt) {
      K2_ISSUE(t + 2, (t + 2) % 3);
      asm volatile("s_waitcnt vmcnt(10)" ::: "memory");   // tile t landed
    } else if (t == nt - 2) {
      asm volatile("s_waitcnt vmcnt(5)" ::: "memory");
    } else {
      asm volatile("s_waitcnt vmcnt(0)" ::: "memory");
    }
    __builtin_amdgcn_sched_barrier(0);
    __builtin_amdgcn_s_barrier();
    asm volatile("" ::: "memory");
#pragma unroll
    for (int rt = 0; rt < 2; rt++) {
      int r = wr * 32 + rt * 16 + l15;
      int rx = (r & 7) << 2;
      float4 u = *reinterpret_cast<const float4*>(&Ab[bufc][r * 32 + ((kg * 8) ^ rx)]);
      float4 v = *reinterpret_cast<const float4*>(&Ab[bufc][r * 32 + ((kg * 8 + 4) ^ rx)]);
      short8v af;
      af[0] = f2bf(u.x); af[1] = f2bf(u.y); af[2] = f2bf(u.z); af[3] = f2bf(u.w);
      af[4] = f2bf(v.x); af[5] = f2bf(v.y); af[6] = f2bf(v.z); af[7] = f2bf(v.w);
#pragma unroll
      for (int ct = 0; ct < 6; ct++) {
        short8v bf = *reinterpret_cast<const short8v*>(&Bb[bufc][bOff[ct]]);
        // swapped operands: acc row(kg*4+e) = j, col(l15) = n
        acc[rt][ct] = __builtin_amdgcn_mfma_f32_16x16x32_bf16(bf, af, acc[rt][ct], 0, 0, 0);
      }
    }
    __builtin_amdgcn_s_barrier();
  }

  // store: XGP[ch][j][n] -> per 16-lane group 64B contiguous in n; block-exclusive lines
  size_t chbase = (size_t)ch * 768000;
#pragma unroll
  for (int rt = 0; rt < 2; rt++)
#pragma unroll
    for (int ct = 0; ct < 6; ct++)
#pragma unroll
      for (int e = 0; e < 4; e++) {
        int j = wc * 96 + ct * 16 + kg * 4 + e;
        int n = n0 + wr * 32 + rt * 16 + l15;
        XGP[chbase + (size_t)j * 4000 + n] = acc[rt][ct][e];
      }
}

// ---------------- K3: persistent LSTM, f16 MFMA, exp2-domain gates, bias in acc
__global__ __launch_bounds__(256, 4) void lstm_kernel(
    const float* __restrict__ XGP, const unsigned short* __restrict__ Wt2,
    const float* __restrict__ W_gcn, const float* __restrict__ b_gcn,
    const float* __restrict__ b_ih, const float* __restrict__ b_hh,
    const float* __restrict__ W_out, const float* __restrict__ b_out,
    float* __restrict__ out) {
  __shared__ unsigned short A[32 * 128];  // [row][k] f16, XOR-swizzled; k<64: g, k>=64: h
  __shared__ float xga[24 * 32];
  __shared__ float red[8 * 32];

  int tid = threadIdx.x;
  int w = tid >> 6, lane = tid & 63, l15 = lane & 15, kg = lane >> 4;
  int r0 = blockIdx.x * 32;
  int hidx = w * 16 + l15;

  half8 wf[4][4];
#pragma unroll
  for (int ct = 0; ct < 4; ct++) {
    int j = ct * 64 + hidx;
#pragma unroll
    for (int ks = 0; ks < 4; ks++)
      wf[ct][ks] = *reinterpret_cast<const half8*>(&Wt2[j * 128 + ks * 32 + kg * 8]);
  }
  // pre-scaled biases (match Wt2 scaling)
  float bI = (b_ih[hidx] + b_hh[hidx]) * L2E;
  float bF = (b_ih[64 + hidx] + b_hh[64 + hidx]) * L2E;
  float bG = (b_ih[128 + hidx] + b_hh[128 + hidx]) * L2E2;
  float bO = (b_ih[192 + hidx] + b_hh[192 + hidx]) * L2E;
  float wg0 = W_gcn[2 * hidx], wg1 = W_gcn[2 * hidx + 1], bg = b_gcn[hidx];

  for (int i = tid; i < 32 * 128 / 2; i += 256)
    reinterpret_cast<unsigned int*>(A)[i] = 0u;
  // preload xg: sum 7 K-chunk partials; XGP layout [ch][j][4000] -> each (tc,ch)
  // read is one exclusive 128B line per block (r4-proven pattern, FETCH ~11MB)
  for (int i = tid; i < 24 * 32; i += 256) {
    int row = i & 31, tc = i >> 5;
    int g = r0 + row;
    int b = g / 4000, n = g - b * 4000;
    size_t base = (size_t)(b * 24 + tc) * 4000 + n;
    float s = 0.f;
#pragma unroll
    for (int chh = 0; chh < 7; chh++) s += XGP[(size_t)chh * 768000 + base];
    xga[tc * 32 + row] = s;
  }
  float creg[8];
#pragma unroll
  for (int i = 0; i < 8; i++) creg[i] = 0.f;
  __syncthreads();

  for (int t = 0; t < 12; t++) {
    // g-phase
#pragma unroll
    for (int half = 0; half < 2; half++)
#pragma unroll
      for (int rr = 0; rr < 4; rr++) {
        int row = half * 16 + kg * 4 + rr;
        float xg0 = xga[(2 * t) * 32 + row];
        float xg1 = xga[(2 * t + 1) * 32 + row];
        float gv = fmaxf(xg0 * wg0 + xg1 * wg1 + bg, 0.f);
        _Float16 hv = (_Float16)gv;
        A[row * 128 + (hidx ^ ((row & 7) << 3))] = __builtin_bit_cast(unsigned short, hv);
      }
    __syncthreads();

    // gates GEMM [32 x 128] @ [128 x 256], bias preloaded into acc
    floatx4 acc[2][4];
#pragma unroll
    for (int rt = 0; rt < 2; rt++) {
      acc[rt][0] = floatx4{bI, bI, bI, bI};
      acc[rt][1] = floatx4{bF, bF, bF, bF};
      acc[rt][2] = floatx4{bG, bG, bG, bG};
      acc[rt][3] = floatx4{bO, bO, bO, bO};
    }
#pragma unroll
    for (int rt = 0; rt < 2; rt++) {
      int row = rt * 16 + l15;
      int xr = (row & 7) << 3;
      half8 af[4];
#pragma unroll
      for (int ks = 0; ks < 4; ks++)
        af[ks] = *reinterpret_cast<const half8*>(&A[row * 128 + ((ks * 32 + kg * 8) ^ xr)]);
#pragma unroll
      for (int ks = 0; ks < 4; ks++)
#pragma unroll
        for (int ct = 0; ct < 4; ct++)
          acc[rt][ct] = __builtin_amdgcn_mfma_f32_16x16x32_f16(
              af[ks], wf[ct][ks], acc[rt][ct], 0, 0, 0);
    }
    __syncthreads();

    // epilogue: exp2-domain gates (acc already log2e-scaled + biased)
#pragma unroll
    for (int rt = 0; rt < 2; rt++)
#pragma unroll
      for (int e = 0; e < 4; e++) {
        int row = rt * 16 + kg * 4 + e;
        float si = __builtin_amdgcn_rcpf(1.f + __builtin_amdgcn_exp2f(-acc[rt][0][e]));
        float sf = __builtin_amdgcn_rcpf(1.f + __builtin_amdgcn_exp2f(-acc[rt][1][e]));
        float tg = 1.f - 2.f * __builtin_amdgcn_rcpf(1.f + __builtin_amdgcn_exp2f(acc[rt][2][e]));
        float so = __builtin_amdgcn_rcpf(1.f + __builtin_amdgcn_exp2f(-acc[rt][3][e]));
        float c = sf * creg[rt * 4 + e] + si * tg;
        creg[rt * 4 + e] = c;
        float tc = 1.f - 2.f * __builtin_amdgcn_rcpf(1.f + __builtin_amdgcn_exp2f(L2E2 * c));
        float h = so * tc;
        _Float16 hv = (_Float16)h;
        A[row * 128 + ((64 + hidx) ^ ((row & 7) << 3))] = __builtin_bit_cast(unsigned short, hv);
      }
  }
  __syncthreads();

  // output projection
  {
    int rg = tid & 31, kq = tid >> 5;
    float partial = 0.f;
#pragma unroll
    for (int i = 0; i < 8; i++) {
      int k = kq * 8 + i;
      float hv = (float)__builtin_bit_cast(
          _Float16, A[rg * 128 + ((64 + k) ^ ((rg & 7) << 3))]);
      partial += hv * W_out[k];
    }
    red[kq * 32 + rg] = partial;
  }
  __syncthreads();
  if (tid < 32) {
    float s = b_out[0];
#pragma unroll
    for (int i = 0; i < 8; i++) s += red[i * 32 + tid];
    out[r0 + tid] = s;
  }
}

extern "C" void kernel_launch(void* const* d_in, const int* in_sizes, int n_in,
                              void* d_out, int out_size, void* d_ws, size_t ws_size,
                              hipStream_t stream) {
  const float* x     = (const float*)d_in[0];
  const float* adj   = (const float*)d_in[1];
  const float* W_gcn = (const float*)d_in[2];
  const float* b_gcn = (const float*)d_in[3];
  const float* W_ih  = (const float*)d_in[4];
  const float* W_hh  = (const float*)d_in[5];
  const float* b_ih  = (const float*)d_in[6];
  const float* b_hh  = (const float*)d_in[7];
  const float* W_out = (const float*)d_in[8];
  const float* b_out = (const float*)d_in[9];
  float* outp = (float*)d_out;

  float* XGP = (float*)d_ws;                                       // 7*768000 f32 = 21,504,000 B
  unsigned short* XBT = (unsigned short*)((char*)d_ws + 21504000); // 192*4032 bf16
  unsigned short* Wt2 = (unsigned short*)((char*)d_ws + 23052288); // 256*128 f16

  prep_kernel<<<394, 256, 0, stream>>>(x, W_ih, W_hh, XBT, Wt2);
  gcn_gemm_kernel<<<441, 256, 0, stream>>>(adj, XBT, XGP);
  lstm_kernel<<<1000, 256, 0, stream>>>(XGP, Wt2, W_gcn, b_gcn, b_ih, b_hh,
                                        W_out, b_out, outp);
}

// Round 8
// 183.182 us; speedup vs baseline: 1.3297x; 1.3214x over previous
//
#include <hip/hip_runtime.h>

typedef _Float16 half8 __attribute__((ext_vector_type(8)));
typedef short short8v __attribute__((ext_vector_type(8)));
typedef unsigned short ushort4v __attribute__((ext_vector_type(4)));
typedef float floatx4 __attribute__((ext_vector_type(4)));

#define GLOBAL_AS __attribute__((address_space(1)))
#define LDS_AS __attribute__((address_space(3)))
#define L2E 1.44269504f
#define L2E2 2.88539008f

__device__ __forceinline__ unsigned short f2bf(float f) {
  unsigned int u = __float_as_uint(f);
  unsigned int r = (u + 0x7FFFu + ((u >> 16) & 1u)) >> 16;
  return (unsigned short)r;
}

// ---------------- K1: XBT[j][m] bf16 (m pad 4032, zero); Wt2[j][k] f16 PRE-SCALED by
// log2e (i,f,o gates) / 2*log2e (g gate) for exp2-domain LSTM nonlinearities.
__global__ __launch_bounds__(256) void prep_kernel(
    const float* __restrict__ x, const float* __restrict__ W_ih,
    const float* __restrict__ W_hh, unsigned short* __restrict__ XBT,
    unsigned short* __restrict__ Wt2) {
  int idx = blockIdx.x * 256 + threadIdx.x;
  if (idx < 96 * 1008) {
    int bt = idx / 1008;
    int mg = idx - bt * 1008;
    int m0 = mg * 4;
    int j0 = bt * 2;
    ushort4v c0, c1;
    if (m0 < 4000) {
      const float* px = x + ((size_t)bt * 4000 + m0) * 2;
      float4 v0 = *reinterpret_cast<const float4*>(px);
      float4 v1 = *reinterpret_cast<const float4*>(px + 4);
      c0[0] = f2bf(v0.x); c0[1] = f2bf(v0.z); c0[2] = f2bf(v1.x); c0[3] = f2bf(v1.z);
      c1[0] = f2bf(v0.y); c1[1] = f2bf(v0.w); c1[2] = f2bf(v1.y); c1[3] = f2bf(v1.w);
    } else {
      c0 = ushort4v{0, 0, 0, 0};
      c1 = ushort4v{0, 0, 0, 0};
    }
    *reinterpret_cast<ushort4v*>(&XBT[(size_t)j0 * 4032 + m0]) = c0;
    *reinterpret_cast<ushort4v*>(&XBT[(size_t)(j0 + 1) * 4032 + m0]) = c1;
  } else {
    int widx = idx - 96 * 1008;   // exactly 256*16
    int j = widx >> 4, kq = widx & 15;
    float scale = (j >= 128 && j < 192) ? L2E2 : L2E;
    const float* src = (kq < 8) ? (W_ih + j * 64 + kq * 8)
                                : (W_hh + j * 64 + (kq - 8) * 8);
    float4 v0 = *reinterpret_cast<const float4*>(src);
    float4 v1 = *reinterpret_cast<const float4*>(src + 4);
    half8 h;
    h[0] = (_Float16)(v0.x * scale); h[1] = (_Float16)(v0.y * scale);
    h[2] = (_Float16)(v0.z * scale); h[3] = (_Float16)(v0.w * scale);
    h[4] = (_Float16)(v1.x * scale); h[5] = (_Float16)(v1.y * scale);
    h[6] = (_Float16)(v1.z * scale); h[7] = (_Float16)(v1.w * scale);
    *reinterpret_cast<half8*>(&Wt2[j * 128 + kq * 8]) = h;
  }
}

// ---------------- K2: XGP[ch][j][n] partial = sum_{m in chunk} adj[n][m]*x[m][j]
// M-tile 64, K-tile 32, 7 chunks (6x18 + 1x17 tiles) x 63 n-blocks = 441 blocks.
// Ring-3 LDS, 2-deep prefetch, staging via global_load_lds, counted vmcnt.
__global__ __launch_bounds__(256, 2) void gcn_gemm_kernel(
    const float* __restrict__ adj, const unsigned short* __restrict__ XBT,
    float* __restrict__ XGP) {
  __shared__ float Ab[3][2048];            // [64 n][32 k] f32, granule-XOR by (row&7)
  __shared__ unsigned short Bb[3][6144];   // [192 j][32 k] bf16, granule-XOR by ((j>>1)&3)
  int tid = threadIdx.x;
  int w = tid >> 6, lane = tid & 63, l15 = lane & 15, kg = lane >> 4;
  int wr = w >> 1, wc = w & 1;             // 2x2 waves: rows wr*32+, j wc*96+
  int bid = blockIdx.x;
  int ch = bid / 63;                       // 0..6
  int nb = bid - ch * 63;
  int n0 = (nb == 62) ? 3936 : nb * 64;    // last block overlaps (idempotent rewrite)
  int k0 = ch * 576;                       // chunk k origin (18 tiles of 32)
  int nt = (ch == 6) ? 17 : 18;            // 6*18 + 17 = 125 tiles = 4000 k exact

  const float* aS[2];
#pragma unroll
  for (int l = 0; l < 2; l++) {
    int gi = l * 256 + tid;
    int row = gi >> 3, kq = gi & 7;
    aS[l] = adj + (size_t)(n0 + row) * 4000 + k0 + ((kq ^ (row & 7)) << 2);
  }
  const unsigned short* bS[3];
#pragma unroll
  for (int q = 0; q < 3; q++) {
    int gi = q * 256 + tid;
    int j = gi >> 2, gp = gi & 3;
    bS[q] = XBT + (size_t)j * 4032 + k0 + ((gp ^ ((j >> 1) & 3)) << 3);
  }
  int bOff[6];
#pragma unroll
  for (int ct = 0; ct < 6; ct++) {
    int j = wc * 96 + ct * 16 + l15;
    bOff[ct] = j * 32 + ((kg ^ ((j >> 1) & 3)) << 3);
  }

#define K2_ISSUE(tt, bf)                                                       \
  {                                                                            \
    _Pragma("unroll")                                                          \
    for (int l = 0; l < 2; l++)                                                \
      __builtin_amdgcn_global_load_lds(                                        \
          (const GLOBAL_AS unsigned int*)(aS[l] + (tt) * 32),                  \
          (LDS_AS unsigned int*)&Ab[(bf)][l * 1024 + w * 256], 16, 0, 0);      \
    _Pragma("unroll")                                                          \
    for (int q = 0; q < 3; q++)                                                \
      __builtin_amdgcn_global_load_lds(                                        \
          (const GLOBAL_AS unsigned int*)(bS[q] + (tt) * 32),                  \
          (LDS_AS unsigned int*)&Bb[(bf)][q * 2048 + w * 512], 16, 0, 0);      \
  }

  floatx4 acc[2][6];
#pragma unroll
  for (int rt = 0; rt < 2; rt++)
#pragma unroll
    for (int ct = 0; ct < 6; ct++) acc[rt][ct] = floatx4{0.f, 0.f, 0.f, 0.f};

  K2_ISSUE(0, 0);
  K2_ISSUE(1, 1);
  for (int t = 0; t < nt; t++) {
    int bufc = t % 3;
    if (t + 2 < nt) {
      K2_ISSUE(t + 2, (t + 2) % 3);
      asm volatile("s_waitcnt vmcnt(10)" ::: "memory");   // tile t landed
    } else if (t == nt - 2) {
      asm volatile("s_waitcnt vmcnt(5)" ::: "memory");
    } else {
      asm volatile("s_waitcnt vmcnt(0)" ::: "memory");
    }
    __builtin_amdgcn_sched_barrier(0);
    __builtin_amdgcn_s_barrier();
    asm volatile("" ::: "memory");
#pragma unroll
    for (int rt = 0; rt < 2; rt++) {
      int r = wr * 32 + rt * 16 + l15;
      int rx = (r & 7) << 2;
      float4 u = *reinterpret_cast<const float4*>(&Ab[bufc][r * 32 + ((kg * 8) ^ rx)]);
      float4 v = *reinterpret_cast<const float4*>(&Ab[bufc][r * 32 + ((kg * 8 + 4) ^ rx)]);
      short8v af;
      af[0] = f2bf(u.x); af[1] = f2bf(u.y); af[2] = f2bf(u.z); af[3] = f2bf(u.w);
      af[4] = f2bf(v.x); af[5] = f2bf(v.y); af[6] = f2bf(v.z); af[7] = f2bf(v.w);
#pragma unroll
      for (int ct = 0; ct < 6; ct++) {
        short8v bf = *reinterpret_cast<const short8v*>(&Bb[bufc][bOff[ct]]);
        // swapped operands: acc row(kg*4+e) = j, col(l15) = n
        acc[rt][ct] = __builtin_amdgcn_mfma_f32_16x16x32_bf16(bf, af, acc[rt][ct], 0, 0, 0);
      }
    }
    __builtin_amdgcn_s_barrier();
  }

  size_t chbase = (size_t)ch * 768000;
#pragma unroll
  for (int rt = 0; rt < 2; rt++)
#pragma unroll
    for (int ct = 0; ct < 6; ct++)
#pragma unroll
      for (int e = 0; e < 4; e++) {
        int j = wc * 96 + ct * 16 + kg * 4 + e;
        int n = n0 + wr * 32 + rt * 16 + l15;
        XGP[chbase + (size_t)j * 4000 + n] = acc[rt][ct][e];
      }
}

// ---------------- K3: persistent LSTM, f16 MFMA, exp2-domain gates, bias in acc.
// __launch_bounds__(256,3): wf[4][4] needs 64 VGPRs resident; (256,4) spills
// (r5-r7 regression: VGPR_Count 64, FETCH 158MB scratch traffic, 2x dur).
__global__ __launch_bounds__(256, 3) void lstm_kernel(
    const float* __restrict__ XGP, const unsigned short* __restrict__ Wt2,
    const float* __restrict__ W_gcn, const float* __restrict__ b_gcn,
    const float* __restrict__ b_ih, const float* __restrict__ b_hh,
    const float* __restrict__ W_out, const float* __restrict__ b_out,
    float* __restrict__ out) {
  __shared__ unsigned short A[32 * 128];  // [row][k] f16, XOR-swizzled; k<64: g, k>=64: h
  __shared__ float xga[24 * 32];
  __shared__ float red[8 * 32];

  int tid = threadIdx.x;
  int w = tid >> 6, lane = tid & 63, l15 = lane & 15, kg = lane >> 4;
  int r0 = blockIdx.x * 32;
  int hidx = w * 16 + l15;

  half8 wf[4][4];
#pragma unroll
  for (int ct = 0; ct < 4; ct++) {
    int j = ct * 64 + hidx;
#pragma unroll
    for (int ks = 0; ks < 4; ks++)
      wf[ct][ks] = *reinterpret_cast<const half8*>(&Wt2[j * 128 + ks * 32 + kg * 8]);
  }
  float bI = (b_ih[hidx] + b_hh[hidx]) * L2E;
  float bF = (b_ih[64 + hidx] + b_hh[64 + hidx]) * L2E;
  float bG = (b_ih[128 + hidx] + b_hh[128 + hidx]) * L2E2;
  float bO = (b_ih[192 + hidx] + b_hh[192 + hidx]) * L2E;
  float wg0 = W_gcn[2 * hidx], wg1 = W_gcn[2 * hidx + 1], bg = b_gcn[hidx];

  for (int i = tid; i < 32 * 128 / 2; i += 256)
    reinterpret_cast<unsigned int*>(A)[i] = 0u;
  for (int i = tid; i < 24 * 32; i += 256) {
    int row = i & 31, tc = i >> 5;
    int g = r0 + row;
    int b = g / 4000, n = g - b * 4000;
    size_t base = (size_t)(b * 24 + tc) * 4000 + n;
    float s = 0.f;
#pragma unroll
    for (int chh = 0; chh < 7; chh++) s += XGP[(size_t)chh * 768000 + base];
    xga[tc * 32 + row] = s;
  }
  float creg[8];
#pragma unroll
  for (int i = 0; i < 8; i++) creg[i] = 0.f;
  __syncthreads();

  for (int t = 0; t < 12; t++) {
    // g-phase
#pragma unroll
    for (int half = 0; half < 2; half++)
#pragma unroll
      for (int rr = 0; rr < 4; rr++) {
        int row = half * 16 + kg * 4 + rr;
        float xg0 = xga[(2 * t) * 32 + row];
        float xg1 = xga[(2 * t + 1) * 32 + row];
        float gv = fmaxf(xg0 * wg0 + xg1 * wg1 + bg, 0.f);
        _Float16 hv = (_Float16)gv;
        A[row * 128 + (hidx ^ ((row & 7) << 3))] = __builtin_bit_cast(unsigned short, hv);
      }
    __syncthreads();

    // gates GEMM [32 x 128] @ [128 x 256], bias preloaded into acc
    floatx4 acc[2][4];
#pragma unroll
    for (int rt = 0; rt < 2; rt++) {
      acc[rt][0] = floatx4{bI, bI, bI, bI};
      acc[rt][1] = floatx4{bF, bF, bF, bF};
      acc[rt][2] = floatx4{bG, bG, bG, bG};
      acc[rt][3] = floatx4{bO, bO, bO, bO};
    }
#pragma unroll
    for (int rt = 0; rt < 2; rt++) {
      int row = rt * 16 + l15;
      int xr = (row & 7) << 3;
      half8 af[4];
#pragma unroll
      for (int ks = 0; ks < 4; ks++)
        af[ks] = *reinterpret_cast<const half8*>(&A[row * 128 + ((ks * 32 + kg * 8) ^ xr)]);
#pragma unroll
      for (int ks = 0; ks < 4; ks++)
#pragma unroll
        for (int ct = 0; ct < 4; ct++)
          acc[rt][ct] = __builtin_amdgcn_mfma_f32_16x16x32_f16(
              af[ks], wf[ct][ks], acc[rt][ct], 0, 0, 0);
    }
    __syncthreads();

    // epilogue: exp2-domain gates (acc already log2e-scaled + biased)
#pragma unroll
    for (int rt = 0; rt < 2; rt++)
#pragma unroll
      for (int e = 0; e < 4; e++) {
        int row = rt * 16 + kg * 4 + e;
        float si = __builtin_amdgcn_rcpf(1.f + __builtin_amdgcn_exp2f(-acc[rt][0][e]));
        float sf = __builtin_amdgcn_rcpf(1.f + __builtin_amdgcn_exp2f(-acc[rt][1][e]));
        float tg = 1.f - 2.f * __builtin_amdgcn_rcpf(1.f + __builtin_amdgcn_exp2f(acc[rt][2][e]));
        float so = __builtin_amdgcn_rcpf(1.f + __builtin_amdgcn_exp2f(-acc[rt][3][e]));
        float c = sf * creg[rt * 4 + e] + si * tg;
        creg[rt * 4 + e] = c;
        float tc = 1.f - 2.f * __builtin_amdgcn_rcpf(1.f + __builtin_amdgcn_exp2f(L2E2 * c));
        float h = so * tc;
        _Float16 hv = (_Float16)h;
        A[row * 128 + ((64 + hidx) ^ ((row & 7) << 3))] = __builtin_bit_cast(unsigned short, hv);
      }
  }
  __syncthreads();

  // output projection
  {
    int rg = tid & 31, kq = tid >> 5;
    float partial = 0.f;
#pragma unroll
    for (int i = 0; i < 8; i++) {
      int k = kq * 8 + i;
      float hv = (float)__builtin_bit_cast(
          _Float16, A[rg * 128 + ((64 + k) ^ ((rg & 7) << 3))]);
      partial += hv * W_out[k];
    }
    red[kq * 32 + rg] = partial;
  }
  __syncthreads();
  if (tid < 32) {
    float s = b_out[0];
#pragma unroll
    for (int i = 0; i < 8; i++) s += red[i * 32 + tid];
    out[r0 + tid] = s;
  }
}

extern "C" void kernel_launch(void* const* d_in, const int* in_sizes, int n_in,
                              void* d_out, int out_size, void* d_ws, size_t ws_size,
                              hipStream_t stream) {
  const float* x     = (const float*)d_in[0];
  const float* adj   = (const float*)d_in[1];
  const float* W_gcn = (const float*)d_in[2];
  const float* b_gcn = (const float*)d_in[3];
  const float* W_ih  = (const float*)d_in[4];
  const float* W_hh  = (const float*)d_in[5];
  const float* b_ih  = (const float*)d_in[6];
  const float* b_hh  = (const float*)d_in[7];
  const float* W_out = (const float*)d_in[8];
  const float* b_out = (const float*)d_in[9];
  float* outp = (float*)d_out;

  float* XGP = (float*)d_ws;                                       // 7*768000 f32 = 21,504,000 B
  unsigned short* XBT = (unsigned short*)((char*)d_ws + 21504000); // 192*4032 bf16
  unsigned short* Wt2 = (unsigned short*)((char*)d_ws + 23052288); // 256*128 f16

  prep_kernel<<<394, 256, 0, stream>>>(x, W_ih, W_hh, XBT, Wt2);
  gcn_gemm_kernel<<<441, 256, 0, stream>>>(adj, XBT, XGP);
  lstm_kernel<<<1000, 256, 0, stream>>>(XGP, Wt2, W_gcn, b_gcn, b_ih, b_hh,
                                        W_out, b_out, outp);
}